// Round 1
// 278.740 us; speedup vs baseline: 1.0108x; 1.0108x over previous
//
#include <hip/hip_runtime.h>

typedef __bf16 bf16;
typedef bf16 bf16x8 __attribute__((ext_vector_type(8)));
typedef float f32x4 __attribute__((ext_vector_type(4)));
typedef unsigned short ushort;
typedef ushort ushort4v __attribute__((ext_vector_type(4)));

#define BB 8192   // batch
#define NN 2048   // nodes

// ---------------------------------------------------------------------------
__device__ __forceinline__ void async16(const void* g, void* l) {
    __builtin_amdgcn_global_load_lds(
        (__attribute__((address_space(1))) void*)(void*)g,
        (__attribute__((address_space(3))) void*)l,
        16, 0, 0);
}

// ---------------------------------------------------------------------------
// K1: gather-conv, 2 batch rows/block, nodes packed (x0,l0,x1,l1) in one
// float4 -> ONE ds_read_b128 per node serves both rows.
// Node index XOR-swizzled (n ^= (n>>3)&7, bijective) so the staging stores
// (which otherwise all land in banks (16i+4j)%32 -> 32-way conflict) spread
// across all 8 bank-quads; gather reads are random either way.
__global__ __launch_bounds__(256) void conv_gather(
    const float* __restrict__ x, const float* __restrict__ label,
    const int* __restrict__ adj, const float* __restrict__ cw,
    const float* __restrict__ cb, bf16* __restrict__ V) {
    __shared__ float4 sxl[NN];   // 32 KB
    const int bb0 = blockIdx.x * 2;
    const int t   = threadIdx.x;

    const float4* x0 = (const float4*)(x     + (size_t)bb0 * NN);
    const float4* x1 = (const float4*)(x     + (size_t)(bb0 + 1) * NN);
    const float4* l0 = (const float4*)(label + (size_t)bb0 * NN);
    const float4* l1 = (const float4*)(label + (size_t)(bb0 + 1) * NN);
#pragma unroll
    for (int q = 0; q < 2; ++q) {
        int i = q * 256 + t;             // float4 index, 512 per row
        float4 a = x0[i], b = l0[i], c = x1[i], d = l1[i];
        int n0i = i * 4;
        int sx  = (i >> 1) & 7;          // == ((n0i+j)>>3)&7 for j=0..3
        sxl[(n0i + 0) ^ sx] = make_float4(a.x, b.x, c.x, d.x);
        sxl[(n0i + 1) ^ sx] = make_float4(a.y, b.y, c.y, d.y);
        sxl[(n0i + 2) ^ sx] = make_float4(a.z, b.z, c.z, d.z);
        sxl[(n0i + 3) ^ sx] = make_float4(a.w, b.w, c.w, d.w);
    }
    const float w0 = cw[0], w1 = cw[1], w2 = cw[2], w3 = cw[3];
    const float w4 = cw[4], w5 = cw[5], w6 = cw[6], w7 = cw[7];
    const float bias = cb[0];

    const int4* adj4 = (const int4*)adj;
    int4 a[8];
#pragma unroll
    for (int j = 0; j < 8; ++j) a[j] = adj4[t * 8 + j];

    __syncthreads();

    bf16 o0[8], o1[8];
#pragma unroll
    for (int j = 0; j < 8; ++j) {
        int4 aa = a[j];
        float4 p0 = sxl[aa.x ^ ((aa.x >> 3) & 7)];
        float4 p1 = sxl[aa.y ^ ((aa.y >> 3) & 7)];
        float4 p2 = sxl[aa.z ^ ((aa.z >> 3) & 7)];
        float4 p3 = sxl[aa.w ^ ((aa.w >> 3) & 7)];
        float v0 = bias
                 + w0 * p0.x + w1 * p1.x + w2 * p2.x + w3 * p3.x
                 + w4 * p0.y + w5 * p1.y + w6 * p2.y + w7 * p3.y;
        float v1 = bias
                 + w0 * p0.z + w1 * p1.z + w2 * p2.z + w3 * p3.z
                 + w4 * p0.w + w5 * p1.w + w6 * p2.w + w7 * p3.w;
        o0[j] = (bf16)fmaxf(v0, 0.0f);
        o1[j] = (bf16)fmaxf(v1, 0.0f);
    }
    *(bf16x8*)(V + (size_t)bb0 * NN + t * 8)       = *(const bf16x8*)o0;
    *(bf16x8*)(V + (size_t)(bb0 + 1) * NN + t * 8) = *(const bf16x8*)o1;
}

// ---------------------------------------------------------------------------
// K2: fused (a) transpose V (8192x2048 bf16) -> Y2 (2048x8192), blocks 0..4095
//           (b) lin_w f32 -> bf16 (4.19M floats),               blocks 4096..6143
__global__ __launch_bounds__(256) void transp_cvtw(
    const ushort* __restrict__ V, ushort* __restrict__ Y,
    const float* __restrict__ W, bf16* __restrict__ Wb) {
    const int b = blockIdx.x;
    if (b >= 4096) {
        size_t i = (size_t)(b - 4096) * 256 + threadIdx.x;
        float4 v0 = ((const float4*)W)[i * 2 + 0];
        float4 v1 = ((const float4*)W)[i * 2 + 1];
        bf16x8 o;
        o[0] = (bf16)v0.x; o[1] = (bf16)v0.y; o[2] = (bf16)v0.z; o[3] = (bf16)v0.w;
        o[4] = (bf16)v1.x; o[5] = (bf16)v1.y; o[6] = (bf16)v1.z; o[7] = (bf16)v1.w;
        ((bf16x8*)Wb)[i] = o;
        return;
    }
    __shared__ ushort tile[64][68];
    const int g0 = (b & 31) * 64;    // V col / Y row
    const int p0 = (b >> 5) * 64;    // V row / Y col
    const int c  = threadIdx.x & 15;
    const int r4 = threadIdx.x >> 4;

#pragma unroll
    for (int pass = 0; pass < 4; ++pass) {
        int r = pass * 16 + r4;
        ushort4v v = *(const ushort4v*)(V + (size_t)(p0 + r) * NN + g0 + c * 4);
        *(ushort4v*)&tile[r][c * 4] = v;
    }
    __syncthreads();
#pragma unroll
    for (int pass = 0; pass < 4; ++pass) {
        int r = pass * 16 + r4;
        ushort4v o;
        o.x = tile[c * 4 + 0][r];
        o.y = tile[c * 4 + 1][r];
        o.z = tile[c * 4 + 2][r];
        o.w = tile[c * 4 + 3][r];
        *(ushort4v*)(Y + (size_t)(g0 + r) * BB + p0 + c * 4) = o;
    }
}

// ---------------------------------------------------------------------------
// K3: out(8192x2048) = A * W^T + bias.
// 256x256 tile, BK=64, 8 waves (2Mx4N), 512 threads, 128 KiB LDS.
// 8-phase schedule (T3+T4): per phase {ds_read quadrant frags || stage one
// 128-row half-tile via global_load_lds -> s_barrier -> lgkmcnt(0) ->
// setprio(1) + 16 MFMA + setprio(0) -> [vmcnt(4) at ph4/ph8] -> s_barrier}.
// Even K-tiles -> buf0, odd -> buf1 (static, no pointer swap).
// T2 swizzle: LDS [256][64] bf16 rows are 128B; frag reads of 16 rows at one
// 16B slot would be 16-way conflicted. slot_phys = slot_log ^ (row&7) applied
// as pre-swizzled GLOBAL source (linear LDS dest, rule #21) + swizzled read.
// vmcnt ledger: 4 outstanding entering each iter; ph1-4 add 8 -> vmcnt(4)
// completes the 8 oldest (= everything ph5 needs); same at ph8. Never 0.
__global__ __launch_bounds__(512, 2) void gemm_bt(
    const bf16* __restrict__ A, const bf16* __restrict__ W,
    const float* __restrict__ bias, float* __restrict__ out) {
    __shared__ __attribute__((aligned(16))) bf16 sA[2][16384];
    __shared__ __attribute__((aligned(16))) bf16 sB[2][16384];

    const int t    = threadIdx.x;
    const int lane = t & 63;
    const int wv   = t >> 6;
    const int wm   = wv & 1;     // 2 M-waves
    const int wn   = wv >> 1;    // 4 N-waves
    const int l16  = lane & 15;
    const int l4   = lane >> 4;

    // XCD-stripe mapping: by = id&7 -> each XCD owns one full B panel (1 MB,
    // L2-resident); 32 bx blocks per stripe = 32 CUs per XCD. 256 blocks total.
    const int bx = blockIdx.x >> 3;
    const int by = blockIdx.x & 7;
    const int m0 = bx * 256;
    const int n0 = by * 256;

    // staging: thread t covers (row = t>>3, slot = t&7) of a 64-row round;
    // source k-slot pre-swizzled so linear LDS dest holds swizzled layout.
    const int r8  = t >> 3;
    const int c8  = ((t & 7) ^ (r8 & 7)) * 8;
    const int dst = t * 8;

    // fragment read offsets (bf16 elements into a [256][64] tile)
    const int sw    = l16 & 7;
    const int aOff0 = (wm * 128 + l16) * 64 + ((l4    ) ^ sw) * 8;  // ks=0
    const int aOff1 = (wm * 128 + l16) * 64 + ((l4 + 4) ^ sw) * 8;  // ks=1
    const int bOff0 = (wn * 64  + l16) * 64 + ((l4    ) ^ sw) * 8;
    const int bOff1 = (wn * 64  + l16) * 64 + ((l4 + 4) ^ sw) * 8;

    f32x4  acc[8][4] = {};
    bf16x8 aR[4][2], bR[4][2];

#define GBAR()  asm volatile("s_barrier" ::: "memory")
#define LGKM0() asm volatile("s_waitcnt lgkmcnt(0)" ::: "memory")
#define VMW4()  asm volatile("s_waitcnt vmcnt(4)" ::: "memory")
#define VMW0()  asm volatile("s_waitcnt vmcnt(0)" ::: "memory")

#define STG(G, rb, kt, lp) do {                                           \
        const bf16* _s = (G) + (size_t)((rb) + r8) * 2048 + (kt) + c8;    \
        async16(_s, (lp) + dst);                                          \
        async16(_s + (size_t)64 * 2048, (lp) + 4096 + dst);               \
    } while (0)

#define LDA(sp, mh) do {                                                  \
        const bf16* _p = (sp) + (mh) * 4096;                              \
        aR[0][0] = *(const bf16x8*)(_p + aOff0);                          \
        aR[0][1] = *(const bf16x8*)(_p + aOff1);                          \
        aR[1][0] = *(const bf16x8*)(_p + 1024 + aOff0);                   \
        aR[1][1] = *(const bf16x8*)(_p + 1024 + aOff1);                   \
        aR[2][0] = *(const bf16x8*)(_p + 2048 + aOff0);                   \
        aR[2][1] = *(const bf16x8*)(_p + 2048 + aOff1);                   \
        aR[3][0] = *(const bf16x8*)(_p + 3072 + aOff0);                   \
        aR[3][1] = *(const bf16x8*)(_p + 3072 + aOff1);                   \
    } while (0)

#define LDB(sp, nh) do {                                                  \
        const bf16* _p = (sp) + (nh) * 2048;                              \
        bR[(nh)*2+0][0] = *(const bf16x8*)(_p + bOff0);                   \
        bR[(nh)*2+0][1] = *(const bf16x8*)(_p + bOff1);                   \
        bR[(nh)*2+1][0] = *(const bf16x8*)(_p + 1024 + bOff0);            \
        bR[(nh)*2+1][1] = *(const bf16x8*)(_p + 1024 + bOff1);            \
    } while (0)

#define MM(mh, nh) do {                                                   \
        __builtin_amdgcn_s_setprio(1);                                    \
        _Pragma("unroll")                                                 \
        for (int _mf = 0; _mf < 4; ++_mf)                                 \
            _Pragma("unroll")                                             \
            for (int _nf = 0; _nf < 2; ++_nf) {                           \
                acc[(mh)*4+_mf][(nh)*2+_nf] =                             \
                    __builtin_amdgcn_mfma_f32_16x16x32_bf16(              \
                        aR[_mf][0], bR[(nh)*2+_nf][0],                    \
                        acc[(mh)*4+_mf][(nh)*2+_nf], 0, 0, 0);            \
                acc[(mh)*4+_mf][(nh)*2+_nf] =                             \
                    __builtin_amdgcn_mfma_f32_16x16x32_bf16(              \
                        aR[_mf][1], bR[(nh)*2+_nf][1],                    \
                        acc[(mh)*4+_mf][(nh)*2+_nf], 0, 0, 0);            \
            }                                                             \
        __builtin_amdgcn_s_setprio(0);                                    \
    } while (0)

    bf16* const sA0 = &sA[0][0]; bf16* const sA1 = &sA[1][0];
    bf16* const sB0 = &sB[0][0]; bf16* const sB1 = &sB[1][0];

    // prologue: tile0 A+B -> buf0, tile1 B -> buf1 (12 loads); keep tile1-B
    // in flight (vmcnt(4)).
    STG(A, m0,       0,  sA0);
    STG(A, m0 + 128, 0,  sA0 + 8192);
    STG(W, n0,       0,  sB0);
    STG(W, n0 + 128, 0,  sB0 + 8192);
    STG(W, n0,       64, sB1);
    STG(W, n0 + 128, 64, sB1 + 8192);
    VMW4();
    GBAR();

    for (int i = 0; i < 15; ++i) {
        const int kb = i * 128;
        // ph1: Q(0,0) of buf0; stage A(2i+1).h0 -> sA1 (dead since prev ph7)
        LDA(sA0, 0); LDB(sB0, 0);
        STG(A, m0, kb + 64, sA1);
        GBAR(); LGKM0();
        MM(0, 0);
        GBAR();
        // ph2: Q(0,1); stage A(2i+1).h1
        LDB(sB0, 1);
        STG(A, m0 + 128, kb + 64, sA1 + 8192);
        GBAR(); LGKM0();
        MM(0, 1);
        GBAR();
        // ph3: Q(1,0); stage B(2i+2).h0 -> sB0 (B-buf0 dead after ph2)
        LDA(sA0, 1);
        STG(W, n0, kb + 128, sB0);
        GBAR(); LGKM0();
        MM(1, 0);
        GBAR();
        // ph4: Q(1,1); stage B(2i+2).h1; vmcnt(4) -> A(2i+1)+B(2i+1) landed
        STG(W, n0 + 128, kb + 128, sB0 + 8192);
        GBAR(); LGKM0();
        MM(1, 1);
        VMW4();
        GBAR();
        // ph5: Q(0,0) of buf1; stage A(2i+2).h0 -> sA0 (A-buf0 dead after ph3)
        LDA(sA1, 0); LDB(sB1, 0);
        STG(A, m0, kb + 128, sA0);
        GBAR(); LGKM0();
        MM(0, 0);
        GBAR();
        // ph6
        LDB(sB1, 1);
        STG(A, m0 + 128, kb + 128, sA0 + 8192);
        GBAR(); LGKM0();
        MM(0, 1);
        GBAR();
        // ph7: stage B(2i+3).h0 -> sB1 (B-buf1 dead after ph6)
        LDA(sA1, 1);
        STG(W, n0, kb + 192, sB1);
        GBAR(); LGKM0();
        MM(1, 0);
        GBAR();
        // ph8: stage B(2i+3).h1; vmcnt(4) -> A(2i+2)+B(2i+2) landed
        STG(W, n0 + 128, kb + 192, sB1 + 8192);
        GBAR(); LGKM0();
        MM(1, 1);
        VMW4();
        GBAR();
    }

    // final iteration (tiles 30, 31): only A(31) remains to stage
    LDA(sA0, 0); LDB(sB0, 0);
    STG(A, m0, 1984, sA1);
    GBAR(); LGKM0(); MM(0, 0); GBAR();
    LDB(sB0, 1);
    STG(A, m0 + 128, 1984, sA1 + 8192);
    GBAR(); LGKM0(); MM(0, 1); GBAR();
    LDA(sA0, 1);
    GBAR(); LGKM0(); MM(1, 0); GBAR();
    GBAR(); LGKM0(); MM(1, 1);
    VMW0();                      // epilogue drain: B(31)+A(31) landed
    GBAR();
    LDA(sA1, 0); LDB(sB1, 0);
    GBAR(); LGKM0(); MM(0, 0); GBAR();
    LDB(sB1, 1);
    GBAR(); LGKM0(); MM(0, 1); GBAR();
    LDA(sA1, 1);
    GBAR(); LGKM0(); MM(1, 0); GBAR();
    GBAR(); LGKM0(); MM(1, 1);

    // epilogue: bias + store (regs only; no barrier needed)
#pragma unroll
    for (int nf = 0; nf < 4; ++nf) {
        const int col = n0 + wn * 64 + nf * 16 + l16;
        const float bc = bias[col];
#pragma unroll
        for (int mf = 0; mf < 8; ++mf) {
            const size_t row = (size_t)(m0 + wm * 128 + mf * 16 + l4 * 4);
#pragma unroll
            for (int rr = 0; rr < 4; ++rr)
                out[(row + rr) * 2048 + col] = acc[mf][nf][rr] + bc;
        }
    }
#undef STG
#undef LDA
#undef LDB
#undef MM
#undef GBAR
#undef LGKM0
#undef VMW4
#undef VMW0
}

// ---------------------------------------------------------------------------
extern "C" void kernel_launch(void* const* d_in, const int* in_sizes, int n_in,
                              void* d_out, int out_size, void* d_ws, size_t ws_size,
                              hipStream_t stream) {
    (void)in_sizes; (void)n_in; (void)out_size; (void)ws_size;
    const float* x     = (const float*)d_in[0];
    const float* label = (const float*)d_in[1];
    const int*   adj   = (const int*)d_in[2];
    const float* cw    = (const float*)d_in[3];
    const float* cb    = (const float*)d_in[4];
    const float* lw    = (const float*)d_in[5];
    const float* lb    = (const float*)d_in[6];
    float* out = (float*)d_out;

    // scratch: V (32MB) in d_out (overwritten by GEMM), Y2 at ws, Wb at ws+32MB
    bf16* V  = (bf16*)d_out;
    bf16* Y2 = (bf16*)d_ws;
    bf16* Wb = (bf16*)((char*)d_ws + (size_t)2048 * 8192 * 2);

    conv_gather<<<BB / 2, 256, 0, stream>>>(x, label, adj, cw, cb, V);
    transp_cvtw<<<6144, 256, 0, stream>>>((const ushort*)V, (ushort*)Y2,
                                          lw, Wb);
    gemm_bt<<<dim3(256), 512, 0, stream>>>(Y2, Wb, lb, out);
}

// Round 3
// 269.276 us; speedup vs baseline: 1.0463x; 1.0351x over previous
//
#include <hip/hip_runtime.h>

typedef __bf16 bf16;
typedef bf16 bf16x8 __attribute__((ext_vector_type(8)));
typedef float f32x4 __attribute__((ext_vector_type(4)));
typedef unsigned short ushort;
typedef ushort ushort4v __attribute__((ext_vector_type(4)));

#define BB 8192   // batch
#define NN 2048   // nodes

// ---------------------------------------------------------------------------
__device__ __forceinline__ void async16(const void* g, void* l) {
    __builtin_amdgcn_global_load_lds(
        (__attribute__((address_space(1))) void*)(void*)g,
        (__attribute__((address_space(3))) void*)l,
        16, 0, 0);
}

// ---------------------------------------------------------------------------
// K1: gather-conv, 2 batch rows/block, nodes packed (x0,l0,x1,l1) in one
// float4 -> ONE ds_read_b128 per node serves both rows.
__global__ __launch_bounds__(256) void conv_gather(
    const float* __restrict__ x, const float* __restrict__ label,
    const int* __restrict__ adj, const float* __restrict__ cw,
    const float* __restrict__ cb, bf16* __restrict__ V) {
    __shared__ float4 sxl[NN];   // 32 KB
    const int bb0 = blockIdx.x * 2;
    const int t   = threadIdx.x;

    const float4* x0 = (const float4*)(x     + (size_t)bb0 * NN);
    const float4* x1 = (const float4*)(x     + (size_t)(bb0 + 1) * NN);
    const float4* l0 = (const float4*)(label + (size_t)bb0 * NN);
    const float4* l1 = (const float4*)(label + (size_t)(bb0 + 1) * NN);
#pragma unroll
    for (int q = 0; q < 2; ++q) {
        int i = q * 256 + t;             // float4 index, 512 per row
        float4 a = x0[i], b = l0[i], c = x1[i], d = l1[i];
        int n0i = i * 4;
        int sx  = (i >> 1) & 7;          // == ((n0i+j)>>3)&7 for j=0..3
        sxl[(n0i + 0) ^ sx] = make_float4(a.x, b.x, c.x, d.x);
        sxl[(n0i + 1) ^ sx] = make_float4(a.y, b.y, c.y, d.y);
        sxl[(n0i + 2) ^ sx] = make_float4(a.z, b.z, c.z, d.z);
        sxl[(n0i + 3) ^ sx] = make_float4(a.w, b.w, c.w, d.w);
    }
    const float w0 = cw[0], w1 = cw[1], w2 = cw[2], w3 = cw[3];
    const float w4 = cw[4], w5 = cw[5], w6 = cw[6], w7 = cw[7];
    const float bias = cb[0];

    const int4* adj4 = (const int4*)adj;
    int4 a[8];
#pragma unroll
    for (int j = 0; j < 8; ++j) a[j] = adj4[t * 8 + j];

    __syncthreads();

    bf16 o0[8], o1[8];
#pragma unroll
    for (int j = 0; j < 8; ++j) {
        int4 aa = a[j];
        float4 p0 = sxl[aa.x ^ ((aa.x >> 3) & 7)];
        float4 p1 = sxl[aa.y ^ ((aa.y >> 3) & 7)];
        float4 p2 = sxl[aa.z ^ ((aa.z >> 3) & 7)];
        float4 p3 = sxl[aa.w ^ ((aa.w >> 3) & 7)];
        float v0 = bias
                 + w0 * p0.x + w1 * p1.x + w2 * p2.x + w3 * p3.x
                 + w4 * p0.y + w5 * p1.y + w6 * p2.y + w7 * p3.y;
        float v1 = bias
                 + w0 * p0.z + w1 * p1.z + w2 * p2.z + w3 * p3.z
                 + w4 * p0.w + w5 * p1.w + w6 * p2.w + w7 * p3.w;
        o0[j] = (bf16)fmaxf(v0, 0.0f);
        o1[j] = (bf16)fmaxf(v1, 0.0f);
    }
    *(bf16x8*)(V + (size_t)bb0 * NN + t * 8)       = *(const bf16x8*)o0;
    *(bf16x8*)(V + (size_t)(bb0 + 1) * NN + t * 8) = *(const bf16x8*)o1;
}

// ---------------------------------------------------------------------------
// K2: fused (a) transpose V (8192x2048 bf16) -> Y2 (2048x8192), blocks 0..4095
//           (b) lin_w f32 -> bf16 (4.19M floats),               blocks 4096..6143
// Transpose read side: 4x ds_read_b64 + in-register 4x4 ushort transpose
// (was 16x ds_read_u16 per thread).
__global__ __launch_bounds__(256) void transp_cvtw(
    const ushort* __restrict__ V, ushort* __restrict__ Y,
    const float* __restrict__ W, bf16* __restrict__ Wb) {
    const int b = blockIdx.x;
    if (b >= 4096) {
        size_t i = (size_t)(b - 4096) * 256 + threadIdx.x;
        float4 v0 = ((const float4*)W)[i * 2 + 0];
        float4 v1 = ((const float4*)W)[i * 2 + 1];
        bf16x8 o;
        o[0] = (bf16)v0.x; o[1] = (bf16)v0.y; o[2] = (bf16)v0.z; o[3] = (bf16)v0.w;
        o[4] = (bf16)v1.x; o[5] = (bf16)v1.y; o[6] = (bf16)v1.z; o[7] = (bf16)v1.w;
        ((bf16x8*)Wb)[i] = o;
        return;
    }
    __shared__ __attribute__((aligned(16))) ushort tile[64][68];
    const int g0 = (b & 31) * 64;    // V col / Y row
    const int p0 = (b >> 5) * 64;    // V row / Y col
    const int c  = threadIdx.x & 15;
    const int r4 = threadIdx.x >> 4;   // [0,16)

#pragma unroll
    for (int pass = 0; pass < 4; ++pass) {
        int r = pass * 16 + r4;
        ushort4v v = *(const ushort4v*)(V + (size_t)(p0 + r) * NN + g0 + c * 4);
        *(ushort4v*)&tile[r][c * 4] = v;
    }
    __syncthreads();
    // thread (c, r4) emits Y rows g0 + r4*4 + q, cols p0 + c*4 + j
    ushort4v rv[4];
#pragma unroll
    for (int j = 0; j < 4; ++j)
        rv[j] = *(const ushort4v*)&tile[c * 4 + j][r4 * 4];
#pragma unroll
    for (int q = 0; q < 4; ++q) {
        ushort4v o;
        o.x = rv[0][q]; o.y = rv[1][q]; o.z = rv[2][q]; o.w = rv[3][q];
        *(ushort4v*)(Y + (size_t)(g0 + r4 * 4 + q) * BB + p0 + c * 4) = o;
    }
}

// ---------------------------------------------------------------------------
// K3: out(8192x2048) = A * W^T + bias.
// 256x256 tile, BK=64, 8 waves (2Mx4N), 512 threads, 128 KiB LDS.
// m201-ledger 8-phase schedule; stages at earliest liveness-legal phase so
// every vmcnt(6) wait targets loads issued >=3 phases earlier.
// Stage plan (iter i, buf0 = tile 2i, buf1 = tile 2i+1):
//   ph1: A(2i+1).h1->sA1   ph3: B(2i+2).h0->sB0
//   ph4: B(2i+2).h1->sB0, A(2i+2).h0->sA0   [vmcnt(6): all of tile 2i+1 landed]
//   ph5: A(2i+2).h1->sA0   ph7: B(2i+3).h0->sB1
//   ph8: B(2i+3).h1->sB1, A(2i+3).h0->sA1   [vmcnt(6): all of tile 2i+2 landed]
// Ledger (2 async16/STG): enter iter with 6 outstanding {B(2i+1).h0,.h1,
// A(2i+1).h0}; ph1:8 -> ph3:10 -> ph4:14 wait(6) retires 8 oldest (= rest of
// tile 2i+1) -> ph5:8 -> ph7:10 -> ph8:14 wait(6) retires tile 2i+2. Never 0.
// PROLOGUE (R2 bug fixed): must establish the SAME invariant -> issue
// A(0),B(0),B(1),A(1).h0 = 14 ops, vmcnt(6) retires the 8 oldest = all of
// tile 0; leaves exactly {B(1).h0,.h1,A(1).h0}. (R2 omitted A(1).h0 -> ph5
// of iter 0 read uninitialized LDS -> NaN; and 12-op prologue left B(0).h1
// unretired at ph1.)
__global__ __launch_bounds__(512, 2) void gemm_bt(
    const bf16* __restrict__ A, const bf16* __restrict__ W,
    const float* __restrict__ bias, float* __restrict__ out) {
    __shared__ __attribute__((aligned(16))) bf16 sA[2][16384];
    __shared__ __attribute__((aligned(16))) bf16 sB[2][16384];

    const int t    = threadIdx.x;
    const int lane = t & 63;
    const int wv   = t >> 6;
    const int wm   = wv & 1;     // 2 M-waves
    const int wn   = wv >> 1;    // 4 N-waves
    const int l16  = lane & 15;
    const int l4   = lane >> 4;

    // Chunked XCD mapping: each XCD owns 4 bx (A panels, 1MB each -> L2-homed)
    // x all 8 by, dispatched by-fastest. Bijective for 256 blocks / 8 XCDs.
    const int xcd = blockIdx.x & 7;
    const int loc = blockIdx.x >> 3;        // [0,32)
    const int bx  = xcd * 4 + (loc >> 3);   // [0,32)
    const int by  = loc & 7;                // [0,8)
    const int m0  = bx * 256;
    const int n0  = by * 256;

    const int r8  = t >> 3;
    const int c8  = ((t & 7) ^ (r8 & 7)) * 8;
    const int dst = t * 8;

    const int sw    = l16 & 7;
    const int aOff0 = (wm * 128 + l16) * 64 + ((l4    ) ^ sw) * 8;
    const int aOff1 = (wm * 128 + l16) * 64 + ((l4 + 4) ^ sw) * 8;
    const int bOff0 = (wn * 64  + l16) * 64 + ((l4    ) ^ sw) * 8;
    const int bOff1 = (wn * 64  + l16) * 64 + ((l4 + 4) ^ sw) * 8;

    f32x4  acc[8][4] = {};
    bf16x8 aR[4][2], bR[4][2];

#define GBAR()  asm volatile("s_barrier" ::: "memory")
#define LGKM0() do { asm volatile("s_waitcnt lgkmcnt(0)" ::: "memory"); \
                     __builtin_amdgcn_sched_barrier(0); } while (0)
#define VMW6()  asm volatile("s_waitcnt vmcnt(6)" ::: "memory")
#define VMW0()  asm volatile("s_waitcnt vmcnt(0)" ::: "memory")

#define STG(G, rb, kt, lp) do {                                           \
        const bf16* _s = (G) + (size_t)((rb) + r8) * 2048 + (kt) + c8;    \
        async16(_s, (lp) + dst);                                          \
        async16(_s + (size_t)64 * 2048, (lp) + 4096 + dst);               \
    } while (0)

#define LDA(sp, mh) do {                                                  \
        const bf16* _p = (sp) + (mh) * 4096;                              \
        aR[0][0] = *(const bf16x8*)(_p + aOff0);                          \
        aR[0][1] = *(const bf16x8*)(_p + aOff1);                          \
        aR[1][0] = *(const bf16x8*)(_p + 1024 + aOff0);                   \
        aR[1][1] = *(const bf16x8*)(_p + 1024 + aOff1);                   \
        aR[2][0] = *(const bf16x8*)(_p + 2048 + aOff0);                   \
        aR[2][1] = *(const bf16x8*)(_p + 2048 + aOff1);                   \
        aR[3][0] = *(const bf16x8*)(_p + 3072 + aOff0);                   \
        aR[3][1] = *(const bf16x8*)(_p + 3072 + aOff1);                   \
    } while (0)

#define LDB(sp, nh) do {                                                  \
        const bf16* _p = (sp) + (nh) * 2048;                              \
        bR[(nh)*2+0][0] = *(const bf16x8*)(_p + bOff0);                   \
        bR[(nh)*2+0][1] = *(const bf16x8*)(_p + bOff1);                   \
        bR[(nh)*2+1][0] = *(const bf16x8*)(_p + 1024 + bOff0);            \
        bR[(nh)*2+1][1] = *(const bf16x8*)(_p + 1024 + bOff1);            \
    } while (0)

#define MM(mh, nh) do {                                                   \
        __builtin_amdgcn_s_setprio(1);                                    \
        _Pragma("unroll")                                                 \
        for (int _ks = 0; _ks < 2; ++_ks)                                 \
            _Pragma("unroll")                                             \
            for (int _mf = 0; _mf < 4; ++_mf)                             \
                _Pragma("unroll")                                         \
                for (int _nf = 0; _nf < 2; ++_nf)                         \
                    acc[(mh)*4+_mf][(nh)*2+_nf] =                         \
                        __builtin_amdgcn_mfma_f32_16x16x32_bf16(          \
                            aR[_mf][_ks], bR[(nh)*2+_nf][_ks],            \
                            acc[(mh)*4+_mf][(nh)*2+_nf], 0, 0, 0);        \
        __builtin_amdgcn_s_setprio(0);                                    \
    } while (0)

    bf16* const sA0 = &sA[0][0]; bf16* const sA1 = &sA[1][0];
    bf16* const sB0 = &sB[0][0]; bf16* const sB1 = &sB[1][0];

    // prologue: A(0)+B(0) (8 ops), then B(1)+A(1).h0 (6 ops) = 14 total.
    // VMW6 retires the 8 oldest = ALL of tile 0; leaves the steady-state
    // invariant {B(1).h0, B(1).h1, A(1).h0} outstanding (issue order matches
    // ph7/ph8 order).
    STG(A, m0,       0,  sA0);
    STG(A, m0 + 128, 0,  sA0 + 8192);
    STG(W, n0,       0,  sB0);
    STG(W, n0 + 128, 0,  sB0 + 8192);
    STG(W, n0,       64, sB1);
    STG(W, n0 + 128, 64, sB1 + 8192);
    STG(A, m0,       64, sA1);          // A(1).h0 — the R2 fix
    VMW6();
    GBAR();

    for (int i = 0; i < 15; ++i) {
        const int kb = i * 128;
        // ph1: stage A(2i+1).h1 (sA1.h1 dead since prev ph7)
        LDA(sA0, 0); LDB(sB0, 0);
        STG(A, m0 + 128, kb + 64, sA1 + 8192);
        GBAR(); LGKM0();
        MM(0, 0);
        GBAR();
        // ph2: no stage
        LDB(sB0, 1);
        GBAR(); LGKM0();
        MM(0, 1);
        GBAR();
        // ph3: stage B(2i+2).h0 (sB0 dead after ph2)
        LDA(sA0, 1);
        STG(W, n0, kb + 128, sB0);
        GBAR(); LGKM0();
        MM(1, 0);
        GBAR();
        // ph4: stage B(2i+2).h1 + A(2i+2).h0 (sA0 dead after ph3); wait buf1
        STG(W, n0 + 128, kb + 128, sB0 + 8192);
        STG(A, m0,       kb + 128, sA0);
        GBAR(); LGKM0();
        MM(1, 1);
        VMW6();
        GBAR();
        // ph5: stage A(2i+2).h1
        LDA(sA1, 0); LDB(sB1, 0);
        STG(A, m0 + 128, kb + 128, sA0 + 8192);
        GBAR(); LGKM0();
        MM(0, 0);
        GBAR();
        // ph6: no stage
        LDB(sB1, 1);
        GBAR(); LGKM0();
        MM(0, 1);
        GBAR();
        // ph7: stage B(2i+3).h0 (sB1 dead after ph6)
        LDA(sA1, 1);
        STG(W, n0, kb + 192, sB1);
        GBAR(); LGKM0();
        MM(1, 0);
        GBAR();
        // ph8: stage B(2i+3).h1 + A(2i+3).h0 (sA1.h0 dead after ph7); wait buf0
        STG(W, n0 + 128, kb + 192, sB1 + 8192);
        STG(A, m0,       kb + 192, sA1);
        GBAR(); LGKM0();
        MM(1, 1);
        VMW6();
        GBAR();
    }

    // tail: tiles 30 (buf0), 31 (buf1); only A(31).h1 remains to stage
    LDA(sA0, 0); LDB(sB0, 0);
    STG(A, m0 + 128, 1984, sA1 + 8192);
    GBAR(); LGKM0(); MM(0, 0); GBAR();
    LDB(sB0, 1);
    GBAR(); LGKM0(); MM(0, 1); GBAR();
    LDA(sA0, 1);
    GBAR(); LGKM0(); MM(1, 0); GBAR();
    GBAR(); LGKM0(); MM(1, 1);
    VMW0();                      // drain tile 31
    GBAR();
    LDA(sA1, 0); LDB(sB1, 0);
    GBAR(); LGKM0(); MM(0, 0); GBAR();
    LDB(sB1, 1);
    GBAR(); LGKM0(); MM(0, 1); GBAR();
    LDA(sA1, 1);
    GBAR(); LGKM0(); MM(1, 0); GBAR();
    GBAR(); LGKM0(); MM(1, 1);

    // epilogue: bias + store (regs only)
#pragma unroll
    for (int nf = 0; nf < 4; ++nf) {
        const int col = n0 + wn * 64 + nf * 16 + l16;
        const float bc = bias[col];
#pragma unroll
        for (int mf = 0; mf < 8; ++mf) {
            const size_t row = (size_t)(m0 + wm * 128 + mf * 16 + l4 * 4);
#pragma unroll
            for (int rr = 0; rr < 4; ++rr)
                out[(row + rr) * 2048 + col] = acc[mf][nf][rr] + bc;
        }
    }
#undef STG
#undef LDA
#undef LDB
#undef MM
#undef GBAR
#undef LGKM0
#undef VMW6
#undef VMW0
}

// ---------------------------------------------------------------------------
extern "C" void kernel_launch(void* const* d_in, const int* in_sizes, int n_in,
                              void* d_out, int out_size, void* d_ws, size_t ws_size,
                              hipStream_t stream) {
    (void)in_sizes; (void)n_in; (void)out_size; (void)ws_size;
    const float* x     = (const float*)d_in[0];
    const float* label = (const float*)d_in[1];
    const int*   adj   = (const int*)d_in[2];
    const float* cw    = (const float*)d_in[3];
    const float* cb    = (const float*)d_in[4];
    const float* lw    = (const float*)d_in[5];
    const float* lb    = (const float*)d_in[6];
    float* out = (float*)d_out;

    // scratch: V (32MB) in d_out (overwritten by GEMM), Y2 at ws, Wb at ws+32MB
    bf16* V  = (bf16*)d_out;
    bf16* Y2 = (bf16*)d_ws;
    bf16* Wb = (bf16*)((char*)d_ws + (size_t)2048 * 8192 * 2);

    conv_gather<<<BB / 2, 256, 0, stream>>>(x, label, adj, cw, cb, V);
    transp_cvtw<<<6144, 256, 0, stream>>>((const ushort*)V, (ushort*)Y2,
                                          lw, Wb);
    gemm_bt<<<dim3(256), 512, 0, stream>>>(Y2, Wb, lb, out);
}